// Round 9
// baseline (1360.975 us; speedup 1.0000x reference)
//
#include <hip/hip_runtime.h>
#include <math.h>

#define TT 512
#define NN 256
#define HH 512
constexpr float AL = 0.1f;

typedef unsigned int uint;
typedef unsigned long long u64;
typedef unsigned short u16;
typedef _Float16 f16;
typedef f16 f16x8 __attribute__((ext_vector_type(8)));
typedef float f32x4 __attribute__((ext_vector_type(4)));

struct Args {
  const float* initdir; const float* vel; const float* fc_w; const float* fc_b;
  const float* W_in; const float* W_rec; const float* W_out; const float* bias;
  float* out; u64* pbuf;
};

// Replay-safe prologues: tags must start at 0; out is atomicAdd-accumulated.
__global__ void zero_pbuf(u64* p) { p[blockIdx.x * 512 + threadIdx.x] = 0ull; }   // 131072 u64 = 1MB
__global__ void zero_out(float4* p) { p[blockIdx.x * 512 + threadIdx.x] = float4{0.f, 0.f, 0.f, 0.f}; }

// 256 WGs x 512 threads, cooperative. Cluster = 8 WGs (bid>>3 shared) owning 8
// batch rows; WG rank c = bid&7 owns h-cols [64c, 64c+64). MFMA 16x16x32_f16
// with M=8 rows really used (vs r8's M=2): 64 MFMA/WG-step, 8/wave -> 3.4x
// less MFMA pipe time. Exchange: per-cluster act buffer of 2048 tagged u64
// (2 f16 acts | tag32); every WG polls the whole buffer (4 u64/thread,
// coalesced, single LLC latency), unpacks via ds_write_b128. All verified
// r6-r8 protocol elements kept: relaxed agent atomics, tag=t+1, parity
// double-buffer, prologue zeroing.
__global__ __launch_bounds__(512, 1)
void rnn_kernel(Args a) {
  __shared__ alignas(16) u16 actw[8][520];  // [row][col], 520 = 16B-aligned + 4-bank skew
  __shared__ float pred[2][8][64];          // [K-half][row][own col]

  const int tid = threadIdx.x;
  const int wav = tid >> 6, lan = tid & 63;
  const int bid = blockIdx.x;
  const int c = bid & 7;    // rank: col slice
  const int ci = bid >> 3;  // cluster: rows [8ci, 8ci+8)

  // update/ship identity: wave g owns batch row g, lane jj owns col c*64+jj
  const int g = wav, jj = lan;
  const int ucol = c * 64 + jj;
  const int ugn = ci * 8 + g;

  // MFMA identity: wave (nt, h0) computes cols [c*64+nt*16, +16) over K-half h0
  const int nt = wav & 3, h0 = wav >> 2;
  const int l15 = lan & 15, gq = lan >> 4;
  const int ncol = c * 64 + nt * 16 + l15;
  const int arow = l15 & 7;  // lanes l15 8-15 duplicate rows 0-7 (D rows 8-15 unused)

  // ---- W_rec -> B-fragments (f16). k-slot (gq,j) := kb*32 + gq*8 + j, the
  // same formula that builds A below, so the k-mapping cancels (r8-verified).
  f16x8 B[8];
#pragma unroll
  for (int kb = 0; kb < 8; ++kb)
#pragma unroll
    for (int j = 0; j < 8; ++j) {
      const int k = h0 * 256 + kb * 32 + gq * 8 + j;
      B[kb][j] = (f16)a.W_rec[(size_t)k * HH + ncol];
    }

  // per-thread parameters
  const float fw0 = a.fc_w[ucol * 2], fw1 = a.fc_w[ucol * 2 + 1], fb = a.fc_b[ucol];
  const float wi0 = AL * a.W_in[ucol], wi1 = AL * a.W_in[HH + ucol];
  const float bj = AL * a.bias[ucol];
  const float wo0 = a.W_out[ucol * 2], wo1 = a.W_out[ucol * 2 + 1];
  const float id0 = a.initdir[ugn * 2], id1 = a.initdir[ugn * 2 + 1];

  float h = fmaf(id0, fw0, fmaf(id1, fw1, fb));  // h0

  u64* reg0 = a.pbuf + (size_t)ci * 2048;         // parity 0 act region (cluster)
  u64* reg1 = a.pbuf + (size_t)(32 + ci) * 2048;  // parity 1
  const int shipw = g * 256 + c * 32 + (jj >> 1); // this WG's word slot
  const float2* velp = (const float2*)a.vel;
  float* outf = a.out;

  // ship act for (row g, cols 2m,2m+1): one fire-and-forget tagged u64
  auto ship = [&](u64* reg, float act, uint tag) {
    const float aR = __shfl_xor(act, 1);
    if (!(jj & 1)) {
      const uint d = __builtin_bit_cast(uint, __builtin_amdgcn_cvt_pkrtz(act, aR));
      __hip_atomic_store(reg + shipw, (u64)d | ((u64)tag << 32),
                         __ATOMIC_RELAXED, __HIP_MEMORY_SCOPE_AGENT);
    }
  };

  ship(reg0, fmaxf(tanhf(h), 0.0f), 1u);  // act_0, tag 1, parity 0

  for (int t = 0; t < TT; ++t) {
    const float2 xv = velp[t * NN + ugn];

    // ---- poll acts_t: 4 tagged u64/thread (32B coalesced), retry stale only
    {
      const u64* s = ((t & 1) ? reg1 : reg0) + 4 * tid;
      const uint want = (uint)(t + 1);
      u64 v0 = __hip_atomic_load(s + 0, __ATOMIC_RELAXED, __HIP_MEMORY_SCOPE_AGENT);
      u64 v1 = __hip_atomic_load(s + 1, __ATOMIC_RELAXED, __HIP_MEMORY_SCOPE_AGENT);
      u64 v2 = __hip_atomic_load(s + 2, __ATOMIC_RELAXED, __HIP_MEMORY_SCOPE_AGENT);
      u64 v3 = __hip_atomic_load(s + 3, __ATOMIC_RELAXED, __HIP_MEMORY_SCOPE_AGENT);
      for (;;) {
        const bool b0 = (uint)(v0 >> 32) != want, b1 = (uint)(v1 >> 32) != want;
        const bool b2 = (uint)(v2 >> 32) != want, b3 = (uint)(v3 >> 32) != want;
        if (!(b0 | b1 | b2 | b3)) break;
        if (b0) v0 = __hip_atomic_load(s + 0, __ATOMIC_RELAXED, __HIP_MEMORY_SCOPE_AGENT);
        if (b1) v1 = __hip_atomic_load(s + 1, __ATOMIC_RELAXED, __HIP_MEMORY_SCOPE_AGENT);
        if (b2) v2 = __hip_atomic_load(s + 2, __ATOMIC_RELAXED, __HIP_MEMORY_SCOPE_AGENT);
        if (b3) v3 = __hip_atomic_load(s + 3, __ATOMIC_RELAXED, __HIP_MEMORY_SCOPE_AGENT);
      }
      // unpack: low dwords are (act0 | act1<<16) -> 8 u16 cols, one b128 write
      *(uint4*)&actw[wav][8 * lan] =
          make_uint4((uint)v0, (uint)v1, (uint)v2, (uint)v3);
    }
    __syncthreads();  // B1: act_t complete in LDS

    // ---- GEMV via MFMA: wave (nt,h0) -> D[16 rows][16 cols] over K=256
    {
      f32x4 acc = {0.f, 0.f, 0.f, 0.f};
#pragma unroll
      for (int kb = 0; kb < 8; ++kb) {
        const f16x8 A = *(const f16x8*)&actw[arow][h0 * 256 + kb * 32 + gq * 8];
        acc = __builtin_amdgcn_mfma_f32_16x16x32_f16(A, B[kb], acc, 0, 0, 0);
      }
      if (lan < 32) {  // rows 0-7 live in lanes 0-31 (C/D map: row=(lane>>4)*4+reg)
        const int r0 = (lan >> 4) * 4, col = nt * 16 + l15;
#pragma unroll
        for (int r = 0; r < 4; ++r) pred[h0][r0 + r][col] = acc[r];
      }
    }
    __syncthreads();  // B2: pred ready; all actw reads done

    // ---- leaky update; ship act_{t+1} IMMEDIATELY; out-proj under the flight
    const float y = pred[0][g][jj] + pred[1][g][jj];
    h = fmaf(0.9f, h, fmaf(AL, y, fmaf(xv.x, wi0, fmaf(xv.y, wi1, bj))));
    const float act = fmaxf(tanhf(h), 0.0f);
    ship((t & 1) ? reg0 : reg1, act, (uint)(t + 2));  // parity (t+1)&1

    // out[t][ugn][:] += act * W_out over own 64 cols (wave = row g)
    float q0 = act * wo0, q1 = act * wo1;
#pragma unroll
    for (int off = 32; off; off >>= 1) {
      q0 += __shfl_down(q0, off);
      q1 += __shfl_down(q1, off);
    }
    if (lan == 0) {
      atomicAdd(&outf[(t * NN + ugn) * 2 + 0], q0);
      atomicAdd(&outf[(t * NN + ugn) * 2 + 1], q1);
    }
  }
}

extern "C" void kernel_launch(void* const* d_in, const int* in_sizes, int n_in,
                              void* d_out, int out_size, void* d_ws, size_t ws_size,
                              hipStream_t stream) {
  (void)in_sizes; (void)n_in; (void)out_size; (void)ws_size;
  Args a;
  a.initdir = (const float*)d_in[0];
  a.vel     = (const float*)d_in[1];
  a.fc_w    = (const float*)d_in[2];
  a.fc_b    = (const float*)d_in[3];
  a.W_in    = (const float*)d_in[4];
  a.W_rec   = (const float*)d_in[5];
  a.W_out   = (const float*)d_in[6];
  a.bias    = (const float*)d_in[7];
  a.out     = (float*)d_out;
  a.pbuf    = (u64*)d_ws;  // 2 parity x 32 clusters x 2048 u64 = 1MB

  zero_pbuf<<<256, 512, 0, stream>>>(a.pbuf);
  zero_out<<<128, 512, 0, stream>>>((float4*)d_out);  // 262144 f32

  void* args[] = { &a };
  hipLaunchCooperativeKernel((const void*)rnn_kernel, dim3(256), dim3(512),
                             args, 0, stream);
}

// Round 10
// 905.483 us; speedup vs baseline: 1.5030x; 1.5030x over previous
//
#include <hip/hip_runtime.h>
#include <math.h>

#define TT 512
#define NN 256
#define HH 512
constexpr float AL = 0.1f;

typedef unsigned int uint;
typedef unsigned short u16;
typedef _Float16 f16;
typedef f16 f16x8 __attribute__((ext_vector_type(8)));
typedef float f32x4 __attribute__((ext_vector_type(4)));

struct Args {
  const float* initdir; const float* vel; const float* fc_w; const float* fc_b;
  const float* W_in; const float* W_rec; const float* W_out; const float* bias;
  float* out; uint* pbuf;
};

// Replay-safe prologues: tags must start at 0; out is atomicAdd-accumulated.
__global__ void zero_pbuf(uint* p) { p[blockIdx.x * 512 + threadIdx.x] = 0u; }     // 512x512 u32 = 1MB
__global__ void zero_out(float4* p) { p[blockIdx.x * 512 + threadIdx.x] = float4{0.f, 0.f, 0.f, 0.f}; }

// 256 WGs x 512 threads, cooperative. Cluster = 2 WGs (bid, bid^8) sharing 2
// batch rows; WG c owns h-cols [256c,256c+256). Exchange = r8's proven scheme:
// per-thread tagged u32 (act f16 <<16 | tag), relaxed agent atomics, parity
// double-buffer, 2KB/WG-step traffic (r9's whole-buffer poll was 8x that and
// regressed). NEW: K-split pipeline -- GEMV splits into own-K half (acts local,
// runs during the LLC flight) and foreign-K half (after poll lands); the
// out-projection also runs under the flight. MFMA 16x16x32_f16, M=2, same
// HW-verified A/B shared-k-placement and C/D maps as r8.
__global__ __launch_bounds__(512, 1)
void rnn_kernel(Args a) {
  __shared__ uint actw32[2][256];  // act_t f16 pairs [row][colpair], 2KB
  __shared__ float pred[2][256];   // y [row][own col], 2KB

  const int tid = threadIdx.x;
  const int wav = tid >> 6, lan = tid & 63;
  const int bid = blockIdx.x;
  const int kk = bid >> 3;
  const int c = kk & 1;                        // cluster rank (col slice)
  const int grp = (bid & 7) * 16 + (kk >> 1);  // n-group 0..127 (2 rows)
  const int own0 = c * 256, fo0 = (1 - c) * 256;

  // update identity: thread owns h(row g, col ucol)
  const int g = tid >> 8, jj = tid & 255;
  const int ucol = own0 + jj, ugn = grp * 2 + g;

  // MFMA identity: wave covers own cols [wav*32, +32), two 16-col tiles
  const int l15 = lan & 15, gq = lan >> 4;
  const int ncol0 = own0 + wav * 32 + l15;
  const int arow = (l15 < 2) ? l15 : 0;  // lanes 2-15 dup row 0 (D rows unused)

  // ---- W_rec -> B-fragments. k-slot (gq,j) := base + kb*32 + gq*8 + j; the
  // A-fragments below use the same formula, so the HW k-order cancels
  // (r8-verified on HW). half 0 = own k-range, half 1 = foreign k-range.
  f16x8 B0[2][8], B1[2][8];
#pragma unroll
  for (int hf = 0; hf < 2; ++hf) {
    const int kb0 = (hf == 0) ? own0 : fo0;
#pragma unroll
    for (int kb = 0; kb < 8; ++kb)
#pragma unroll
      for (int j = 0; j < 8; ++j) {
        const int k = kb0 + kb * 32 + gq * 8 + j;
        B0[hf][kb][j] = (f16)a.W_rec[(size_t)k * HH + ncol0];
        B1[hf][kb][j] = (f16)a.W_rec[(size_t)k * HH + ncol0 + 16];
      }
  }

  // per-thread parameters
  const float fw0 = a.fc_w[ucol * 2], fw1 = a.fc_w[ucol * 2 + 1], fb = a.fc_b[ucol];
  const float wi0 = AL * a.W_in[ucol], wi1 = AL * a.W_in[HH + ucol];
  const float bj = AL * a.bias[ucol];
  const float wo0 = a.W_out[ucol * 2], wo1 = a.W_out[ucol * 2 + 1];
  const float id0 = a.initdir[ugn * 2], id1 = a.initdir[ugn * 2 + 1];

  uint* shipb = a.pbuf + (size_t)(bid ^ 8) * 1024;  // peer's poll region
  const uint* pollb = a.pbuf + (size_t)bid * 1024;
  const float2* velp = (const float2*)a.vel;
  float* outf = a.out;
  const u16* aw16 = (const u16*)actw32;  // [row*512 + col]

  auto ship = [&](int par, float act, uint tag) {
    const uint pk =
        __builtin_bit_cast(uint, __builtin_amdgcn_cvt_pkrtz(act, 0.f)) & 0xffffu;
    __hip_atomic_store(shipb + par * 512 + tid, (pk << 16) | tag,
                       __ATOMIC_RELAXED, __HIP_MEMORY_SCOPE_AGENT);
  };
  auto own_lds = [&](float act) {  // paired u32, conflict-free
    const float aR = __shfl_xor(act, 1);
    if (!(jj & 1))
      actw32[g][(own0 + jj) >> 1] =
          __builtin_bit_cast(uint, __builtin_amdgcn_cvt_pkrtz(act, aR));
  };
  auto outproj = [&](int tt, float act) {
    float q0 = act * wo0, q1 = act * wo1;
#pragma unroll
    for (int off = 32; off; off >>= 1) {
      q0 += __shfl_down(q0, off);
      q1 += __shfl_down(q1, off);
    }
    if (lan == 0) {
      atomicAdd(&outf[(tt * NN + ugn) * 2 + 0], q0);
      atomicAdd(&outf[(tt * NN + ugn) * 2 + 1], q1);
    }
  };

  float h = fmaf(id0, fw0, fmaf(id1, fw1, fb));  // h0
  float actv = fmaxf(tanhf(h), 0.0f);            // act_0
  ship(0, actv, 1u);
  own_lds(actv);
  __syncthreads();

  for (int t = 0; t < TT; ++t) {
    const float2 xv = velp[t * NN + ugn];
    const uint want = (uint)(t + 1);
    const uint* slot = pollb + (t & 1) * 512 + tid;

    // issue the poll load FIRST; its flight overlaps own-half MFMA + out-proj
    uint v = __hip_atomic_load(slot, __ATOMIC_RELAXED, __HIP_MEMORY_SCOPE_AGENT);

    // ---- own-half GEMV (acts already local): 2 chains x 8 K-blocks
    f32x4 ac0 = {0.f, 0.f, 0.f, 0.f}, ac1 = {0.f, 0.f, 0.f, 0.f};
#pragma unroll
    for (int kb = 0; kb < 8; ++kb) {
      const f16x8 A = *(const f16x8*)(aw16 + arow * 512 + own0 + kb * 32 + gq * 8);
      ac0 = __builtin_amdgcn_mfma_f32_16x16x32_f16(A, B0[0][kb], ac0, 0, 0, 0);
      ac1 = __builtin_amdgcn_mfma_f32_16x16x32_f16(A, B1[0][kb], ac1, 0, 0, 0);
    }

    // ---- out[t-1] from register act (VALU, overlaps MFMA + flight)
    if (t > 0) outproj(t - 1, actv);

    // ---- poll check / retry, then paired foreign LDS write
    while ((v & 0xffffu) != want)
      v = __hip_atomic_load(slot, __ATOMIC_RELAXED, __HIP_MEMORY_SCOPE_AGENT);
    {
      const uint vO = __shfl_xor(v, 1);
      if (!(jj & 1))
        actw32[g][(fo0 + jj) >> 1] = (v >> 16) | (vO & 0xffff0000u);
    }
    __syncthreads();  // B1: foreign acts in LDS

    // ---- foreign-half GEMV
#pragma unroll
    for (int kb = 0; kb < 8; ++kb) {
      const f16x8 A = *(const f16x8*)(aw16 + arow * 512 + fo0 + kb * 32 + gq * 8);
      ac0 = __builtin_amdgcn_mfma_f32_16x16x32_f16(A, B0[1][kb], ac0, 0, 0, 0);
      ac1 = __builtin_amdgcn_mfma_f32_16x16x32_f16(A, B1[1][kb], ac1, 0, 0, 0);
    }
    if (lan < 16) {  // rows 0,1 live in regs 0,1 of lanes 0-15 (verified map)
      const int col = wav * 32 + l15;
      pred[0][col] = ac0[0];
      pred[1][col] = ac0[1];
      pred[0][col + 16] = ac1[0];
      pred[1][col + 16] = ac1[1];
    }
    __syncthreads();  // B2: pred ready; actw reads done

    // ---- leaky update; ship act_{t+1} immediately; stage own half
    const float y = pred[g][jj];
    h = fmaf(0.9f, h, fmaf(AL, y, fmaf(xv.x, wi0, fmaf(xv.y, wi1, bj))));
    actv = fmaxf(tanhf(h), 0.0f);
    ship((t + 1) & 1, actv, (uint)(t + 2));
    own_lds(actv);
    __syncthreads();  // B3: own half visible for next own-MFMA
  }

  outproj(TT - 1, actv);  // out[511] from the final act
}

extern "C" void kernel_launch(void* const* d_in, const int* in_sizes, int n_in,
                              void* d_out, int out_size, void* d_ws, size_t ws_size,
                              hipStream_t stream) {
  (void)in_sizes; (void)n_in; (void)out_size; (void)ws_size;
  Args a;
  a.initdir = (const float*)d_in[0];
  a.vel     = (const float*)d_in[1];
  a.fc_w    = (const float*)d_in[2];
  a.fc_b    = (const float*)d_in[3];
  a.W_in    = (const float*)d_in[4];
  a.W_rec   = (const float*)d_in[5];
  a.W_out   = (const float*)d_in[6];
  a.bias    = (const float*)d_in[7];
  a.out     = (float*)d_out;
  a.pbuf    = (uint*)d_ws;  // 256 WGs x 2 parity x 512 slots x 4B = 1MB

  zero_pbuf<<<512, 512, 0, stream>>>(a.pbuf);
  zero_out<<<128, 512, 0, stream>>>((float4*)d_out);  // 262144 f32

  void* args[] = { &a };
  hipLaunchCooperativeKernel((const void*)rnn_kernel, dim3(256), dim3(512),
                             args, 0, stream);
}